// Round 4
// baseline (322.355 us; speedup 1.0000x reference)
//
#include <hip/hip_runtime.h>
#include <hip/hip_bf16.h>
#include <math.h>

#define B_ 64
#define T_ 512
#define D_ 1024
#define M_ (B_*T_)   // 32768 rows of x flattened [B*T, D]

typedef unsigned short u16;
typedef __attribute__((ext_vector_type(8))) _Float16 f16x8;  // 8 fp16 in 4 VGPRs
typedef __attribute__((ext_vector_type(8))) unsigned short u16x8;
typedef __attribute__((ext_vector_type(4))) float f32x4;

// fp32 -> fp16 RNE, bit pattern
__device__ __forceinline__ u16 f2h(float f) {
  union { _Float16 h; u16 u; } v;
  v.h = (_Float16)f;
  return v.u;
}

__device__ __forceinline__ float h2f(u16 u) {
  union { u16 u; _Float16 h; } v;
  v.u = u;
  return (float)v.h;
}

__device__ __forceinline__ float fast_tanh(float x) {
  // tanh(x) = 1 - 2/(exp(2x)+1); saturates correctly at +/-inf of expf
  return 1.0f - 2.0f / (__expf(2.0f * x) + 1.0f);
}

// async global->LDS, 16B per lane; LDS dest = wave-uniform base + lane*16
__device__ __forceinline__ void gll16(const void* g, void* l) {
  __builtin_amdgcn_global_load_lds(
      (const __attribute__((address_space(1))) unsigned int*)g,
      (__attribute__((address_space(3))) unsigned int*)l, 16, 0, 0);
}

// ---------------- K0: fused cvt — blocks <32768: x fp32->fp16; rest: W -> Wt ------
__global__ __launch_bounds__(256) void cvt_kernel(const float4* __restrict__ x,
                                                  ushort4* __restrict__ xh,
                                                  const float* __restrict__ W,
                                                  u16* __restrict__ wt) {
  __shared__ float tile[32][33];
  const int bid = blockIdx.x;
  if (bid < 32768) {
    int i = bid * 256 + threadIdx.x;
    float4 v = x[i];
    ushort4 o;
    o.x = f2h(v.x); o.y = f2h(v.y); o.z = f2h(v.z); o.w = f2h(v.w);
    xh[i] = o;
  } else {
    const int tb = bid - 32768;                 // 1024 transpose tiles
    const int n0 = (tb & 31) * 32, k0 = (tb >> 5) * 32;
    const int tx = threadIdx.x & 31, ty = threadIdx.x >> 5;  // ty 0..7
#pragma unroll
    for (int ph = 0; ph < 4; ph++)
      tile[ty + ph * 8][tx] = W[(k0 + ty + ph * 8) * D_ + n0 + tx];
    __syncthreads();
#pragma unroll
    for (int ph = 0; ph < 4; ph++)
      wt[(long)(n0 + ty + ph * 8) * D_ + k0 + tx] = f2h(tile[tx][ty + ph * 8]);
  }
}

// ---------------- shared core: 256x128 tile, BK=64, 4 waves (round-0 verified) -------
// BK=64 swizzle: row r (64 elems = 8 chunks of 16B), logical chunk c stored at
// position (c + (r>>1)) & 7. Staging lane (p=lane&7, rl=lane>>3) of group g
// (rows g*8..g*8+7) fetches global chunk (p - (r>>1)) & 7. Per-16-lane phase the
// read hits 8 distinct 4-bank groups, 2 lanes each -> conflict-free (measured 0).
__device__ __forceinline__ void gemm_core256x128(const u16* __restrict__ Abase,
                                                 const u16* __restrict__ Bbase,
                                                 u16* As, u16* Bs, int tid,
                                                 f32x4 (&acc)[8][4]) {
  const int wave = tid >> 6, lane = tid & 63;
  const int p = lane & 7, rl = lane >> 3;    // staging coords within 8-row group

  const u16* gA[8]; u16* lA[8];
#pragma unroll
  for (int i = 0; i < 8; i++) {              // A: 32 groups, 8 per wave
    int g = wave * 8 + i;
    int r = g * 8 + rl;
    int c = (p - (r >> 1)) & 7;
    gA[i] = Abase + (long)r * D_ + c * 8;
    lA[i] = As + g * 512;
  }
  const u16* gB[4]; u16* lB[4];
#pragma unroll
  for (int i = 0; i < 4; i++) {              // B: 16 groups, 4 per wave
    int g = wave * 4 + i;
    int r = g * 8 + rl;
    int c = (p - (r >> 1)) & 7;
    gB[i] = Bbase + (long)r * D_ + c * 8;
    lB[i] = Bs + g * 512;
  }

  const int wrow = (wave >> 1) * 128, wcol = (wave & 1) * 64;
  const int lm = lane & 15, qd = lane >> 4;
  const u16* ra = As + (wrow + lm) * 64;
  const u16* rb = Bs + (wcol + lm) * 64;
  // read-side chunk position: p' = (kk*4 + qd + (m>>1)) & 7; m-tile terms vanish mod 8
  const int pk0 = ((qd + (lm >> 1)) & 7) * 8;
  const int pk1 = ((qd + 4 + (lm >> 1)) & 7) * 8;

  for (int kt = 0; kt < D_; kt += 64) {
#pragma unroll
    for (int i = 0; i < 8; i++) { gll16(gA[i], lA[i]); gA[i] += 64; }
#pragma unroll
    for (int i = 0; i < 4; i++) { gll16(gB[i], lB[i]); gB[i] += 64; }
    __syncthreads();
#pragma unroll
    for (int kk = 0; kk < 2; kk++) {
      const int pk = kk ? pk1 : pk0;
      f16x8 af[8], bfr[4];
#pragma unroll
      for (int i = 0; i < 8; i++) af[i] = *(const f16x8*)(ra + i * 16 * 64 + pk);
#pragma unroll
      for (int i = 0; i < 4; i++) bfr[i] = *(const f16x8*)(rb + i * 16 * 64 + pk);
#pragma unroll
      for (int mi = 0; mi < 8; mi++)
#pragma unroll
        for (int ni = 0; ni < 4; ni++)
          acc[mi][ni] = __builtin_amdgcn_mfma_f32_16x16x32_f16(af[mi], bfr[ni], acc[mi][ni], 0, 0, 0);
    }
    __syncthreads();
  }
}

// ---------------- K1: xw = x @ W  — 256x128 tile, BK=64, 1024 blocks (round-0) -------
__global__ __launch_bounds__(256, 2) void gemm1_kernel(const u16* __restrict__ xh,
                                                       const u16* __restrict__ wt,
                                                       u16* __restrict__ xw) {
  __shared__ u16 As[256 * 64];   // 32 KB
  __shared__ u16 Bs[128 * 64];   // 16 KB
  f32x4 acc[8][4] = {};
  const int tid = threadIdx.x;
  const int bx = blockIdx.x;                 // 1024 blocks
  const int xcd = bx & 7, j = bx >> 3;       // j in [0,128)
  const int mt = xcd * 16 + (j >> 3);        // 128 m-tiles of 256 rows
  const int nt = j & 7;                      // 8 n-tiles of 128
  const long m0 = (long)mt * 256;
  const long n0 = (long)nt * 128;
  gemm_core256x128(xh + m0 * D_, wt + n0 * D_, As, Bs, tid, acc);

  const int wave = tid >> 6, lane = tid & 63;
  const int wrow = (wave >> 1) * 128, wcol = (wave & 1) * 64;
  const int lm2 = lane & 15, qd2 = lane >> 4;
#pragma unroll
  for (int mi = 0; mi < 8; mi++)
#pragma unroll
    for (int ni = 0; ni < 4; ni++) {
      long m = m0 + wrow + mi * 16 + qd2 * 4;  // C/D: row=(lane>>4)*4+reg
      long n = n0 + wcol + ni * 16 + lm2;      //      col=lane&15
      u16* ptr = xw + m * D_ + n;
#pragma unroll
      for (int r = 0; r < 4; r++) ptr[(long)r * D_] = f2h(acc[mi][ni][r]);
    }
}

// ---------------- K2: eij on the SAME 256x128/BK=64 core + fused tanh*cv epilogue ----
// 512 blocks (2/CU, all co-resident). Per batch: 2 m-tiles (256 t-rows) x 4 n-tiles
// (128 s-cols) = 8 blocks; same-batch blocks share one XCD (2 MB working set in L2).
// 8 planes: plane = nt*2 + (wave&1); each plane is a disjoint 64-wide s-slice and
// fully tiles [B,T] via (mt, wrow, mi, qd, r) -> race-free.
__global__ __launch_bounds__(256, 2) void gemm2_kernel(const u16* __restrict__ xw,
                                                       const u16* __restrict__ xh,
                                                       const float* __restrict__ bias,
                                                       const float* __restrict__ cv,
                                                       float* __restrict__ scores_part) {
  __shared__ u16 As[256 * 64];   // 32 KB
  __shared__ u16 Bs[128 * 64];   // 16 KB
  f32x4 acc[8][4] = {};
  const int tid = threadIdx.x;
  const int bx = blockIdx.x;                 // 512 blocks
  const int xcd = bx & 7, j = bx >> 3;       // j in [0,64)
  const int bb = xcd * 8 + (j >> 3);         // 64 batches, 8 per XCD
  const int tile = j & 7;                    // 8 tiles per batch
  const int mt = tile >> 2, nt = tile & 3;   // mt: 2 x 256 t-rows; nt: 4 x 128 s-cols
  const u16* Abase = xw + ((long)bb * T_ + mt * 256) * D_;
  const u16* Bbase = xh + ((long)bb * T_ + nt * 128) * D_;
  gemm_core256x128(Abase, Bbase, As, Bs, tid, acc);

  const int wave = tid >> 6, lane = tid & 63;
  const int wrow = (wave >> 1) * 128, wcol = (wave & 1) * 64;
  const int lm2 = lane & 15, qd2 = lane >> 4;
  float cvv[4], bv[4];
#pragma unroll
  for (int ni = 0; ni < 4; ni++) {
    int s = nt * 128 + wcol + ni * 16 + lm2;
    cvv[ni] = cv[s];
    bv[ni] = bias[s];
  }
  const int plane = nt * 2 + (wave & 1);
  float* dst = scores_part + plane * (B_ * T_) + bb * T_ + mt * 256;
#pragma unroll
  for (int mi = 0; mi < 8; mi++) {
#pragma unroll
    for (int r = 0; r < 4; r++) {
      float p = 0.f;
#pragma unroll
      for (int ni = 0; ni < 4; ni++) p += fast_tanh(acc[mi][ni][r] + bv[ni]) * cvv[ni];
      p += __shfl_xor(p, 1); p += __shfl_xor(p, 2);
      p += __shfl_xor(p, 4); p += __shfl_xor(p, 8);
      if (lm2 == 0) dst[wrow + mi * 16 + qd2 * 4 + r] = p;  // unique (plane,b,t) owner
    }
  }
}

// ---------------- K3: fused masked-softmax + weighted-sum ----------------
// grid (64,4) x 256 thr. Each block: softmax of batch b (redundant x4, cheap),
// a_out written by dq==0 blocks only; then wsum of its 256-d slice (atomic-free).
// wsum loads are 16B/lane (ushort8): lane ln covers d-group (ln&31)*8, t-parity
// ln>>5; partner fold via shfl_xor(32).
__global__ __launch_bounds__(256) void sm_wsum_kernel(const float* __restrict__ sp,
                                                      const unsigned char* __restrict__ m8,
                                                      const u16* __restrict__ xh,
                                                      float* __restrict__ a_out,
                                                      float* __restrict__ out) {
  __shared__ float a_sh[512];
  __shared__ float red[8];
  __shared__ int nonz;
  __shared__ float4 lredA[4][32];
  __shared__ float4 lredB[4][32];
  const int b = blockIdx.x, dq = blockIdx.y, tid = threadIdx.x;
  const int w = tid >> 6, ln = tid & 63;
  if (tid == 0) nonz = 0;
  __syncthreads();
  // detect int32-vs-uint8 bool storage from first 512 mask words
  {
    unsigned char c = m8[tid * 4 + 1] | m8[tid * 4 + 2] | m8[tid * 4 + 3] |
                      m8[(tid + 256) * 4 + 1] | m8[(tid + 256) * 4 + 2] | m8[(tid + 256) * 4 + 3];
    if (c) atomicOr(&nonz, 1);
  }
  __syncthreads();
  const bool is_i32 = (nonz == 0);
  float v[2]; bool valid[2];
#pragma unroll
  for (int h = 0; h < 2; h++) {
    int t = tid + h * 256;
    int idx = b * T_ + t;
    valid[h] = is_i32 ? (m8[(long)idx * 4] != 0) : (m8[idx] != 0);
    float s = 0.f;
#pragma unroll
    for (int pl = 0; pl < 8; pl++) s += sp[pl * (B_ * T_) + idx];
    v[h] = valid[h] ? s : -INFINITY;
  }
  float m = fmaxf(v[0], v[1]);
#pragma unroll
  for (int o = 32; o > 0; o >>= 1) m = fmaxf(m, __shfl_xor(m, o));
  if (ln == 0) red[w] = m;
  __syncthreads();
  const float rowmax = fmaxf(fmaxf(red[0], red[1]), fmaxf(red[2], red[3]));
  float e0 = valid[0] ? expf(v[0] - rowmax) : 0.f;
  float e1 = valid[1] ? expf(v[1] - rowmax) : 0.f;
  float ss = e0 + e1;
#pragma unroll
  for (int o = 32; o > 0; o >>= 1) ss += __shfl_xor(ss, o);
  if (ln == 0) red[4 + w] = ss;
  __syncthreads();
  const float tot = red[4] + red[5] + red[6] + red[7];
  const float a0 = e0 / tot, a1 = e1 / tot;
  a_sh[tid] = a0; a_sh[tid + 256] = a1;
  if (dq == 0) {
    a_out[b * T_ + tid] = a0;
    a_out[b * T_ + tid + 256] = a1;
  }
  __syncthreads();
  // weighted sum: wave w sums t in [w*128,(w+1)*128); lane ln: 8 d's, t-parity ln>>5
  const int dg = (ln & 31) * 8;
  const int tp = ln >> 5;
  const u16* xp = xh + (long)b * T_ * D_ + dq * 256 + dg;
  float4 acA = make_float4(0.f, 0.f, 0.f, 0.f);
  float4 acB = make_float4(0.f, 0.f, 0.f, 0.f);
  for (int i = 0; i < 64; i++) {
    int t = w * 128 + i * 2 + tp;
    float av = a_sh[t];
    u16x8 xv = *(const u16x8*)(xp + (long)t * D_);
    acA.x += av * h2f(xv[0]); acA.y += av * h2f(xv[1]);
    acA.z += av * h2f(xv[2]); acA.w += av * h2f(xv[3]);
    acB.x += av * h2f(xv[4]); acB.y += av * h2f(xv[5]);
    acB.z += av * h2f(xv[6]); acB.w += av * h2f(xv[7]);
  }
  // fold t-parity partner (lane ^ 32 holds the same d-group)
  acA.x += __shfl_xor(acA.x, 32); acA.y += __shfl_xor(acA.y, 32);
  acA.z += __shfl_xor(acA.z, 32); acA.w += __shfl_xor(acA.w, 32);
  acB.x += __shfl_xor(acB.x, 32); acB.y += __shfl_xor(acB.y, 32);
  acB.z += __shfl_xor(acB.z, 32); acB.w += __shfl_xor(acB.w, 32);
  if (tp == 0) { lredA[w][ln] = acA; lredB[w][ln] = acB; }
  __syncthreads();
  if (tid < 32) {
    float4 sA = make_float4(0.f, 0.f, 0.f, 0.f);
    float4 sB = make_float4(0.f, 0.f, 0.f, 0.f);
#pragma unroll
    for (int ww = 0; ww < 4; ww++) {
      float4 a = lredA[ww][tid], bq = lredB[ww][tid];
      sA.x += a.x; sA.y += a.y; sA.z += a.z; sA.w += a.w;
      sB.x += bq.x; sB.y += bq.y; sB.z += bq.z; sB.w += bq.w;
    }
    float* op = out + (long)b * D_ + dq * 256 + tid * 8;
    *(float4*)op = sA;
    *(float4*)(op + 4) = sB;
  }
}

extern "C" void kernel_launch(void* const* d_in, const int* in_sizes, int n_in,
                              void* d_out, int out_size, void* d_ws, size_t ws_size,
                              hipStream_t stream) {
  const float* x = (const float*)d_in[0];
  const unsigned char* mask = (const unsigned char*)d_in[1];
  const float* W = (const float*)d_in[2];
  const float* cv = (const float*)d_in[3];
  const float* bias = (const float*)d_in[4];

  float* out = (float*)d_out;                  // [B,D]
  float* a_out = out + (size_t)B_ * D_;        // [B,T]

  // workspace layout (130 MiB): scores_part (1 MiB, 8 planes) aliases wt (dead after gemm1)
  char* ws = (char*)d_ws;
  u16* xh = (u16*)(ws);                         // fp16 x    [M_, D_]  64 MiB
  u16* wt = (u16*)(ws + 67108864);              // fp16 W^T  [D_, D_]   2 MiB
  float* scores_part = (float*)(ws + 67108864); // fp32 [8][B_,T_] 1 MiB (aliases wt)
  u16* xw = (u16*)(ws + 69206016);              // fp16 x@W  [M_, D_]  64 MiB

  cvt_kernel<<<32768 + 1024, 256, 0, stream>>>((const float4*)x, (ushort4*)xh, W, wt);
  gemm1_kernel<<<1024, 256, 0, stream>>>(xh, wt, xw);
  gemm2_kernel<<<512, 256, 0, stream>>>(xw, xh, bias, cv, scores_part);
  sm_wsum_kernel<<<dim3(B_, 4), 256, 0, stream>>>(scores_part, mask, xh, a_out, out);
}